// Round 4
// baseline (576.347 us; speedup 1.0000x reference)
//
#include <hip/hip_runtime.h>
#include <math.h>

#define DIMC 384
#define NHD  6
#define HD   64
#define WSZ  14
#define NTOK 196
#define NWIN 200
#define NWH  1200
#define MWIN 39200
#define MX   32768
#define MLPD 1536

typedef short short8 __attribute__((ext_vector_type(8)));
typedef float f32x4 __attribute__((ext_vector_type(4)));

__device__ __forceinline__ unsigned short f2bf(float f) {
  unsigned int u = __float_as_uint(f);
  u = (u + 0x7fffu + ((u >> 16) & 1u)) >> 16;
  return (unsigned short)u;
}
__device__ __forceinline__ unsigned int pkbf(float a, float b) {
  unsigned int r; asm("v_cvt_pk_bf16_f32 %0, %1, %2" : "=v"(r) : "v"(a), "v"(b)); return r;
}

typedef const __attribute__((address_space(1))) unsigned int* gptr_t;
typedef __attribute__((address_space(3))) unsigned int* lptr_t;
__device__ __forceinline__ void gload16(const unsigned short* g, unsigned short* l) {
  __builtin_amdgcn_global_load_lds((gptr_t)(const void*)g, (lptr_t)(void*)l, 16, 0, 0);
}

// ---------- weight transpose + bf16 convert: out[n*K+k] = bf16(in[k*N+n]) ----------
__global__ void wtrans_kernel(const float* __restrict__ in, unsigned short* __restrict__ out,
                              int K, int N) {
  int id = blockIdx.x * 256 + threadIdx.x;
  if (id >= K * N) return;
  int n = id / K, k = id - n * K;
  out[id] = f2bf(in[(size_t)k * N + n]);
}

// ---------- relcat: [64][64] bf16, rows 0..26 = relh, 27..53 = relw, rest 0 ----------
__global__ void relprep_kernel(const float* __restrict__ relh, const float* __restrict__ relw,
                               unsigned short* __restrict__ relcat) {
  int id = blockIdx.x * 256 + threadIdx.x;
  if (id >= 64 * 64) return;
  int rc = id >> 6, d = id & 63;
  float v = 0.f;
  if (rc < 27) v = relh[rc * 64 + d];
  else if (rc < 54) v = relw[(rc - 27) * 64 + d];
  relcat[id] = f2bf(v);
}

// ---------- zero vT pad columns 196..207 (so PV garbage-free) ----------
__global__ void vpad_kernel(unsigned short* __restrict__ vT) {
  int id = blockIdx.x * 256 + threadIdx.x;
  if (id >= 76800 * 3) return;
  int row = id / 3, part = id - row * 3;
  *(int2*)(vT + (size_t)row * 208 + 196 + part * 4) = make_int2(0, 0);
}

// ---------- LN1 + window partition -> bf16 windowed tokens ----------
__global__ __launch_bounds__(64) void ln1win_kernel(const float* __restrict__ x,
    const float* __restrict__ w, const float* __restrict__ b, unsigned short* __restrict__ xw) {
  int t = blockIdx.x;
  int lane = threadIdx.x;
  int win = t / NTOK, p = t - win * NTOK;
  int bb = win / 25, rem = win - bb * 25;
  int wi = rem / 5, wj = rem - wi * 5;
  int i = p / WSZ, j = p - i * WSZ;
  int r = wi * WSZ + i, c = wj * WSZ + j;
  unsigned short* o = xw + (size_t)t * DIMC;
  if (r >= 64 || c >= 64) {
    #pragma unroll
    for (int q = 0; q < 6; q++) o[lane + q * 64] = 0;
    return;
  }
  const float* xr = x + (((size_t)bb * 64 + r) * 64 + c) * DIMC;
  float v[6]; float s = 0.f, s2 = 0.f;
  #pragma unroll
  for (int q = 0; q < 6; q++) { float f = xr[lane + q * 64]; v[q] = f; s += f; s2 += f * f; }
  #pragma unroll
  for (int off = 32; off; off >>= 1) { s += __shfl_xor(s, off); s2 += __shfl_xor(s2, off); }
  float mean = s * (1.f / DIMC);
  float var  = s2 * (1.f / DIMC) - mean * mean;
  float rstd = rsqrtf(var + 1e-5f);
  #pragma unroll
  for (int q = 0; q < 6; q++) {
    int d = lane + q * 64;
    o[d] = f2bf((v[q] - mean) * rstd * w[d] + b[d]);
  }
}

// ---------- LN2 ----------
__global__ __launch_bounds__(64) void ln2_kernel(const float* __restrict__ x2,
    const float* __restrict__ w, const float* __restrict__ b, unsigned short* __restrict__ h2) {
  int t = blockIdx.x; int lane = threadIdx.x;
  const float* xr = x2 + (size_t)t * DIMC;
  unsigned short* o = h2 + (size_t)t * DIMC;
  float v[6]; float s = 0.f, s2 = 0.f;
  #pragma unroll
  for (int q = 0; q < 6; q++) { float f = xr[lane + q * 64]; v[q] = f; s += f; s2 += f * f; }
  #pragma unroll
  for (int off = 32; off; off >>= 1) { s += __shfl_xor(s, off); s2 += __shfl_xor(s2, off); }
  float mean = s * (1.f / DIMC);
  float var  = s2 * (1.f / DIMC) - mean * mean;
  float rstd = rsqrtf(var + 1e-5f);
  #pragma unroll
  for (int q = 0; q < 6; q++) {
    int d = lane + q * 64;
    o[d] = f2bf((v[q] - mean) * rstd * w[d] + b[d]);
  }
}

// ---------- m97-structure bf16 MFMA GEMM, SWAPPED operands ----------
// acc = mfma(b, a): lane holds token row = l&15 (fixed), 4 consecutive output cols.
// EPI 0: qkv  -> q,k packed 8B stores; v -> transposed scatter
// EPI 1: proj -> unpartition + bias + residual(x) -> x2 fp32 (float4)
// EPI 2: fc1  -> bias + exact gelu -> bf16 hidden (packed 8B)
// EPI 3: fc2  -> bias + residual(x2) -> d_out fp32 (float4)
template <int EPI>
__global__ __launch_bounds__(256) void gemm_kernel(
    const unsigned short* __restrict__ A, const unsigned short* __restrict__ WT,
    int Mrows, int Kd,
    const float* __restrict__ bias, const float* __restrict__ addin,
    float* __restrict__ outf, unsigned short* __restrict__ outb,
    unsigned short* __restrict__ outb2) {
  __shared__ unsigned short As[128 * 32];   // [row][k] linear, row stride 64B
  __shared__ unsigned short Bs[128 * 32];
  const int row0 = blockIdx.x * 128, col0 = blockIdx.y * 128;
  const int tid = threadIdx.x;
  const int l = tid & 63, wid = tid >> 6;
  const int fr = l & 15, fk = (l >> 4) * 8;
  const int wr = (wid >> 1) * 64, wc = (wid & 1) * 64;
  const int sr = l >> 2, sc = (l & 3) * 8;
  f32x4 acc[4][4] = {};
  const unsigned short* ap = A + (size_t)row0 * Kd;
  const unsigned short* bp = WT + (size_t)col0 * Kd;
  for (int k0 = 0; k0 < Kd; k0 += 32) {
    #pragma unroll
    for (int j = 0; j < 2; j++) {
      int chunk = j * 4 + wid;
      gload16(ap + (size_t)(chunk * 16 + sr) * Kd + k0 + sc, &As[chunk * 512]);
      gload16(bp + (size_t)(chunk * 16 + sr) * Kd + k0 + sc, &Bs[chunk * 512]);
    }
    __syncthreads();
    short8 a[4], b[4];
    #pragma unroll
    for (int fi = 0; fi < 4; fi++) {
      a[fi] = *(const short8*)&As[(wr + fi * 16 + fr) * 32 + fk];
      b[fi] = *(const short8*)&Bs[(wc + fi * 16 + fr) * 32 + fk];
    }
    #pragma unroll
    for (int fi = 0; fi < 4; fi++)
      #pragma unroll
      for (int fj = 0; fj < 4; fj++)
        acc[fi][fj] = __builtin_amdgcn_mfma_f32_16x16x32_bf16(b[fj], a[fi], acc[fi][fj], 0, 0, 0);
    __syncthreads();
  }
  // epilogue: gr = token row (fixed per lane,fi); cols gcb..gcb+3 consecutive
  #pragma unroll
  for (int fi = 0; fi < 4; fi++) {
    const int gr = row0 + wr + fi * 16 + fr;
    if (gr >= Mrows) continue;
    int wv_ = 0, p = 0, valid = 1; size_t pixbase = 0;
    if (EPI == 0 || EPI == 1) { wv_ = gr / NTOK; p = gr - wv_ * NTOK; }
    if (EPI == 1) {
      int bb = wv_ / 25, rem2 = wv_ - bb * 25;
      int wi = rem2 / 5, wj = rem2 - wi * 5;
      int i = p / WSZ, j = p - i * WSZ;
      int rr = wi * WSZ + i, cc = wj * WSZ + j;
      valid = (rr < 64) && (cc < 64);
      pixbase = (((size_t)bb * 64 + rr) * 64 + cc) * DIMC;
    }
    #pragma unroll
    for (int fj = 0; fj < 4; fj++) {
      const int gcb = col0 + wc + fj * 16 + (l >> 4) * 4;
      f32x4 v = acc[fi][fj];
      float4 bv = *(const float4*)&bias[gcb];
      float t0 = v[0] + bv.x, t1 = v[1] + bv.y, t2 = v[2] + bv.z, t3 = v[3] + bv.w;
      if (EPI == 0) {
        int s = gcb / 384, rem = gcb - s * 384;
        int hh = rem >> 6, d0 = gcb & 63;
        int whh = wv_ * NHD + hh;
        if (s < 2) {
          *(int2*)&outb[((size_t)s * NWH + whh) * (NTOK * 64) + p * 64 + d0] =
              make_int2((int)pkbf(t0, t1), (int)pkbf(t2, t3));
        } else {
          unsigned short* vb = outb2 + ((size_t)whh * 64 + d0) * 208 + p;
          vb[0] = f2bf(t0); vb[208] = f2bf(t1); vb[416] = f2bf(t2); vb[624] = f2bf(t3);
        }
      } else if (EPI == 1) {
        if (valid) {
          size_t idx = pixbase + gcb;
          float4 ad = *(const float4*)&addin[idx];
          float4 o = make_float4(t0 + ad.x, t1 + ad.y, t2 + ad.z, t3 + ad.w);
          *(float4*)&outf[idx] = o;
        }
      } else if (EPI == 2) {
        float g0 = 0.5f * t0 * (1.f + erff(t0 * 0.70710678118654752f));
        float g1 = 0.5f * t1 * (1.f + erff(t1 * 0.70710678118654752f));
        float g2 = 0.5f * t2 * (1.f + erff(t2 * 0.70710678118654752f));
        float g3 = 0.5f * t3 * (1.f + erff(t3 * 0.70710678118654752f));
        *(int2*)&outb[(size_t)gr * MLPD + gcb] =
            make_int2((int)pkbf(g0, g1), (int)pkbf(g2, g3));
      } else {
        size_t idx = (size_t)gr * DIMC + gcb;
        float4 ad = *(const float4*)&addin[idx];
        float4 o = make_float4(t0 + ad.x, t1 + ad.y, t2 + ad.z, t3 + ad.w);
        *(float4*)&outf[idx] = o;
      }
    }
  }
}

// ---------- MFMA attention: barrier-free, per-wave state only, V from global ----------
__global__ __launch_bounds__(256) void attn_mfma_kernel(
    const unsigned short* __restrict__ qk_g,   // [2][1200][196][64] bf16
    const unsigned short* __restrict__ vT_g,   // [1200][64][208] bf16 (cols 196..207 zeroed)
    const unsigned short* __restrict__ relcat, // [64][64] bf16
    unsigned short* __restrict__ attnout) {    // [200*196][384] bf16
  __shared__ __align__(16) unsigned short P[4][16][232];
  __shared__ __align__(16) float RELB[4][16][68];
  const int wh = blockIdx.x, y = blockIdx.y;
  const int w = wh / NHD, h = wh - w * NHD;
  const int tid = threadIdx.x;
  const int l15 = tid & 15, g = (tid >> 4) & 3, wv = tid >> 6;
  const unsigned short* qg = qk_g + (size_t)wh * (NTOK * 64);
  const unsigned short* kg = qk_g + (size_t)(NWH + wh) * (NTOK * 64);
  const unsigned short* vg = vT_g + (size_t)wh * 64 * 208;
  const int tbeg = y * 7, tend = y ? 13 : 7;
  for (int tile = tbeg + wv; tile < tend; tile += 4) {
    const int row0 = tile * 16;
    short8 qf[2];
    #pragma unroll
    for (int kk = 0; kk < 2; kk++)
      qf[kk] = *(const short8*)(qg + (size_t)(row0 + l15) * 64 + kk * 32 + g * 8);
    // REL = relcat . Q^T
    f32x4 ar[4] = {};
    #pragma unroll
    for (int t = 0; t < 4; t++)
      #pragma unroll
      for (int kk = 0; kk < 2; kk++) {
        short8 af = *(const short8*)(relcat + (t * 16 + l15) * 64 + kk * 32 + g * 8);
        ar[t] = __builtin_amdgcn_mfma_f32_16x16x32_bf16(af, qf[kk], ar[t], 0, 0, 0);
      }
    #pragma unroll
    for (int t = 0; t < 4; t++)
      #pragma unroll
      for (int r = 0; r < 4; r++)
        RELB[wv][l15][t * 16 + g * 4 + r] = ar[t][r];
    __builtin_amdgcn_wave_barrier();
    // S^T = K . Q^T
    f32x4 as_[13] = {};
    #pragma unroll
    for (int kt = 0; kt < 13; kt++)
      #pragma unroll
      for (int kk = 0; kk < 2; kk++) {
        short8 kf = *(const short8*)(kg + (size_t)(kt * 16 + l15) * 64 + kk * 32 + g * 8);
        as_[kt] = __builtin_amdgcn_mfma_f32_16x16x32_bf16(kf, qf[kk], as_[kt], 0, 0, 0);
      }
    // softmax
    int tok = row0 + l15; int tq = tok < 196 ? tok : 195;
    int qi = tq / 14, qj = tq - qi * 14;
    const float* rbh = &RELB[wv][l15][qi + 13];
    const float* rbw = &RELB[wv][l15][27 + qj + 13];
    float m = -1e30f;
    #pragma unroll
    for (int kt = 0; kt < 13; kt++)
      #pragma unroll
      for (int r = 0; r < 4; r++) {
        int key = kt * 16 + g * 4 + r;
        int ki = key / 14, kj = key - ki * 14;
        float s = as_[kt][r] * 0.125f + rbh[-ki] + rbw[-kj];
        if (kt == 12) s = (g == 0) ? s : -1e30f;
        as_[kt][r] = s; m = fmaxf(m, s);
      }
    m = fmaxf(m, __shfl_xor(m, 16)); m = fmaxf(m, __shfl_xor(m, 32));
    float sum = 0.f;
    #pragma unroll
    for (int kt = 0; kt < 13; kt++)
      #pragma unroll
      for (int r = 0; r < 4; r++) {
        float p = __expf(as_[kt][r] - m);
        as_[kt][r] = p; sum += p;
      }
    sum += __shfl_xor(sum, 16); sum += __shfl_xor(sum, 32);
    float inv = 1.f / sum;
    #pragma unroll
    for (int kt = 0; kt < 13; kt++) {
      *(int2*)&P[wv][l15][kt * 16 + g * 4] =
          make_int2((int)pkbf(as_[kt][0] * inv, as_[kt][1] * inv),
                    (int)pkbf(as_[kt][2] * inv, as_[kt][3] * inv));
    }
    *(int2*)&P[wv][l15][208 + g * 4] = make_int2(0, 0);   // zero pad cols 208..223
    __builtin_amdgcn_wave_barrier();
    // O = P . V : A-frag from P lds, B-frag from global vT
    f32x4 ao[4] = {};
    #pragma unroll
    for (int kk = 0; kk < 7; kk++) {
      short8 pa = *(const short8*)&P[wv][l15][kk * 32 + g * 8];
      int ko = kk * 32 + g * 8; if (ko > 200) ko = 200;   // clamp inside 208-col row
      #pragma unroll
      for (int dt = 0; dt < 4; dt++) {
        short8 vb = *(const short8*)(vg + (size_t)(dt * 16 + l15) * 208 + ko);
        ao[dt] = __builtin_amdgcn_mfma_f32_16x16x32_bf16(pa, vb, ao[dt], 0, 0, 0);
      }
    }
    #pragma unroll
    for (int dt = 0; dt < 4; dt++)
      #pragma unroll
      for (int r = 0; r < 4; r++) {
        int tk = row0 + g * 4 + r;
        if (tk < 196)
          attnout[((size_t)w * NTOK + tk) * DIMC + h * 64 + dt * 16 + l15] = f2bf(ao[dt][r]);
      }
  }
}

extern "C" void kernel_launch(void* const* d_in, const int* in_sizes, int n_in,
                              void* d_out, int out_size, void* d_ws, size_t ws_size,
                              hipStream_t stream) {
  const float* x     = (const float*)d_in[0];
  const float* ln1w  = (const float*)d_in[1];
  const float* ln1b  = (const float*)d_in[2];
  const float* qkvw  = (const float*)d_in[3];
  const float* qkvb  = (const float*)d_in[4];
  const float* projw = (const float*)d_in[5];
  const float* projb = (const float*)d_in[6];
  const float* relh  = (const float*)d_in[7];
  const float* relw  = (const float*)d_in[8];
  const float* ln2w  = (const float*)d_in[9];
  const float* ln2b  = (const float*)d_in[10];
  const float* fc1w  = (const float*)d_in[11];
  const float* fc1b  = (const float*)d_in[12];
  const float* fc2w  = (const float*)d_in[13];
  const float* fc2b  = (const float*)d_in[14];

  // workspace regions:
  // R0: xw bf16 (30.1MB) -> x2 f32 (50.3MB)
  // R1: qk bf16 (60.2MB) + vT bf16 (31.9MB) -> hidden bf16 (100.7MB)
  // R2: attnout bf16 (30.1MB) -> h2 bf16 (25.2MB)
  // R3: transposed bf16 weights + relcat
  const size_t R0 = 0;
  const size_t R1 = R0 + 50331648;
  const size_t R2 = R1 + 100663296;
  const size_t R3 = R2 + 30105600;
  const size_t NEED = R3 + 3547136;
  if (ws_size < NEED) return;
  char* ws = (char*)d_ws;
  unsigned short* xw     = (unsigned short*)(ws + R0);
  float*          x2     = (float*)(ws + R0);
  unsigned short* qk_g   = (unsigned short*)(ws + R1);
  unsigned short* vT_g   = qk_g + (size_t)2 * NWH * NTOK * 64;
  unsigned short* hidden = (unsigned short*)(ws + R1);
  unsigned short* attno  = (unsigned short*)(ws + R2);
  unsigned short* h2     = (unsigned short*)(ws + R2);
  unsigned short* qkvwT  = (unsigned short*)(ws + R3);
  unsigned short* projwT = qkvwT + 442368;
  unsigned short* fc1wT  = projwT + 147456;
  unsigned short* fc2wT  = fc1wT + 589824;
  unsigned short* relcat = fc2wT + 589824;

  wtrans_kernel<<<1728, 256, 0, stream>>>(qkvw, qkvwT, 384, 1152);
  wtrans_kernel<<<576, 256, 0, stream>>>(projw, projwT, 384, 384);
  wtrans_kernel<<<2304, 256, 0, stream>>>(fc1w, fc1wT, 384, 1536);
  wtrans_kernel<<<2304, 256, 0, stream>>>(fc2w, fc2wT, 1536, 384);
  relprep_kernel<<<16, 256, 0, stream>>>(relh, relw, relcat);
  vpad_kernel<<<900, 256, 0, stream>>>(vT_g);
  ln1win_kernel<<<MWIN, 64, 0, stream>>>(x, ln1w, ln1b, xw);
  gemm_kernel<0><<<dim3(307, 9), 256, 0, stream>>>(xw, qkvwT, MWIN, 384, qkvb, nullptr, nullptr, qk_g, vT_g);
  attn_mfma_kernel<<<dim3(NWH, 2), 256, 0, stream>>>(qk_g, vT_g, relcat, attno);
  gemm_kernel<1><<<dim3(307, 3), 256, 0, stream>>>(attno, projwT, MWIN, 384, projb, x, x2, nullptr, nullptr);
  ln2_kernel<<<MX, 64, 0, stream>>>(x2, ln2w, ln2b, h2);
  gemm_kernel<2><<<dim3(256, 12), 256, 0, stream>>>(h2, fc1wT, MX, 384, fc1b, nullptr, nullptr, hidden, nullptr);
  gemm_kernel<3><<<dim3(256, 3), 256, 0, stream>>>(hidden, fc2wT, MX, 1536, fc2b, x2, (float*)d_out, nullptr, nullptr);
}